// Round 5
// baseline (762.220 us; speedup 1.0000x reference)
//
#include <hip/hip_runtime.h>

typedef __bf16 bf16_t;
typedef __bf16 bf16x8 __attribute__((ext_vector_type(8)));
typedef __bf16 bf16x4 __attribute__((ext_vector_type(4)));
typedef float  f32x4  __attribute__((ext_vector_type(4)));

#define SEQ   2048
#define DMODEL 1024
#define DFF   4096
#define NHEAD 16
#define HDIM  64
#define MTOK  8192   // 4 * 2048

// ---------------- workspace layout (bytes) ----------------
#define MB (size_t)(1024*1024)
static const size_t XB_OFF   = 0;          // bf16 [8192][1024]  (aliased by FFN1 later)
static const size_t Q_OFF    = 16*MB;      // bf16 [B,H,S,64]
static const size_t K_OFF    = 32*MB;      // bf16 [B,H,S,64]
static const size_t VT_OFF   = 48*MB;      // bf16 [B,H,64,S]
static const size_t FFN1_OFF = 0;          // bf16 [8192][4096] aliases XB..VT (all dead then)
static const size_t CTX_OFF  = 64*MB;      // bf16 [8192][1024]
static const size_t OUT1_OFF = 80*MB;      // f32  [8192][1024]; bias-concat scratch earlier
static const size_t LN1_OFF  = 112*MB;     // bf16 [8192][1024]
static const size_t WQKV_OFF = 128*MB;     // bf16 [3072][1024] (Q,K,V rows concat)
static const size_t WO_OFF   = 134*MB;
static const size_t W1_OFF   = 136*MB;     // bf16 [4096][1024]
static const size_t W2_OFF   = 144*MB;     // bf16 [1024][4096]  (ends at 152MB)

// ---------------- helpers ----------------
__device__ inline void gload16(const void* g, void* l) {
    __builtin_amdgcn_global_load_lds((__attribute__((address_space(1))) void*)g,
                                     (__attribute__((address_space(3))) void*)l, 16, 0, 0);
}

__global__ __launch_bounds__(256) void cast_bf16_k(const float* __restrict__ s,
                                                   bf16_t* __restrict__ d, int n8) {
    int i = blockIdx.x * 256 + threadIdx.x;
    if (i >= n8) return;
    float4 v0 = ((const float4*)s)[2*i];
    float4 v1 = ((const float4*)s)[2*i+1];
    bf16x8 o;
    o[0]=(bf16_t)v0.x; o[1]=(bf16_t)v0.y; o[2]=(bf16_t)v0.z; o[3]=(bf16_t)v0.w;
    o[4]=(bf16_t)v1.x; o[5]=(bf16_t)v1.y; o[6]=(bf16_t)v1.z; o[7]=(bf16_t)v1.w;
    *(bf16x8*)(d + (size_t)i*8) = o;
}

__global__ __launch_bounds__(256) void concat_bias_k(const float* __restrict__ a,
                                                     const float* __restrict__ b,
                                                     const float* __restrict__ c,
                                                     float* __restrict__ o) {
    int i = blockIdx.x * 256 + threadIdx.x;   // grid 12*256 = 3072
    o[i] = (i < 1024) ? a[i] : ((i < 2048) ? b[i - 1024] : c[i - 2048]);
}

// ---------------- GEMM: C = (A(MxK) * B(NxK)^T + bias) * scale ----------------
// EPI 2: fp32 + bias -> out (out1)
// EPI 3: relu -> bf16 (ffn1)
// EPI 4: fp32 + bias + aux[r,c] -> out (s2 = out1+out2, may alias aux)
// EPI 5: fused QKV (N=3072, bias concat'd): mat0 -> Q scatter *0.125, mat1 -> K scatter,
//        mat2 -> V^T scatter. out=Q, out_k=K, out_v=V^T.
template<int EPI>
__global__ __launch_bounds__(256, 2) void gemm_bt(
    const bf16_t* __restrict__ A, const bf16_t* __restrict__ Bm,
    const float* __restrict__ bias, void* __restrict__ out,
    void* __restrict__ out_k, void* __restrict__ out_v,
    const float* __restrict__ aux, int M, int N, int K, float scale)
{
    __shared__ bf16_t As[128*64];
    __shared__ bf16_t Bs[128*64];
    const int tid = threadIdx.x;
    const int l   = tid & 63;
    const int wid = tid >> 6;
    const int wm  = wid >> 1, wn = wid & 1;
    const int c16 = l & 15,   g  = l >> 4;
    // XCD-aware bijective swizzle (all grids have nwg % 8 == 0)
    int lin = blockIdx.y * gridDim.x + blockIdx.x;
    int nwg = gridDim.x * gridDim.y;
    int swz = (lin & 7) * (nwg >> 3) + (lin >> 3);
    const long brow = (long)(swz / gridDim.x) * 128;
    const long bcol = (long)(swz % gridDim.x) * 128;

    f32x4 acc[4][4] = {};

    const int nkt = K >> 6;
    for (int kt = 0; kt < nkt; ++kt) {
        __syncthreads();   // protect LDS while other waves may still be reading
        const bf16_t* Ag = A  + brow * K + kt*64;
        const bf16_t* Bg = Bm + bcol * K + kt*64;
#pragma unroll
        for (int c = 0; c < 4; ++c) {
            int e   = (c*256 + tid) * 8;     // flat bf16 element in 128x64 tile
            int row = e >> 6;
            int col = e & 63;
            gload16(Ag + (long)row*K + col, &As[e]);
            gload16(Bg + (long)row*K + col, &Bs[e]);
        }
        __syncthreads();   // drains vmcnt(0): LDS tiles ready
#pragma unroll
        for (int kk = 0; kk < 2; ++kk) {
            bf16x8 af[4], bfr[4];
#pragma unroll
            for (int mi = 0; mi < 4; ++mi)
                af[mi] = *(const bf16x8*)&As[(wm*64 + mi*16 + c16)*64 + kk*32 + 8*g];
#pragma unroll
            for (int ni = 0; ni < 4; ++ni)
                bfr[ni] = *(const bf16x8*)&Bs[(wn*64 + ni*16 + c16)*64 + kk*32 + 8*g];
#pragma unroll
            for (int mi = 0; mi < 4; ++mi)
#pragma unroll
                for (int ni = 0; ni < 4; ++ni)
                    acc[mi][ni] = __builtin_amdgcn_mfma_f32_16x16x32_bf16(
                        af[mi], bfr[ni], acc[mi][ni], 0, 0, 0);
        }
    }

    // epilogue: lane l, reg i -> row = ...+ g*4 + i, col = ...+ c16
#pragma unroll
    for (int ni = 0; ni < 4; ++ni) {
        const long c = bcol + wn*64 + ni*16 + c16;
        const float bv = bias[c];
#pragma unroll
        for (int mi = 0; mi < 4; ++mi) {
#pragma unroll
            for (int i = 0; i < 4; ++i) {
                const long r = brow + wm*64 + mi*16 + g*4 + i;
                float v = (acc[mi][ni][i] + bv) * scale;
                if constexpr (EPI == 2) {
                    ((float*)out)[r*N + c] = v;
                } else if constexpr (EPI == 3) {
                    ((bf16_t*)out)[r*N + c] = (bf16_t)fmaxf(v, 0.f);
                } else if constexpr (EPI == 4) {
                    ((float*)out)[r*N + c] = v + aux[r*N + c];
                } else if constexpr (EPI == 5) {
                    const int mat = (int)(c >> 10);
                    const int hc  = (int)(c & 1023);
                    const long bb = r >> 11, sidx = r & (SEQ-1);
                    const long hb = bb*NHEAD + (hc >> 6);
                    if (mat == 0)
                        ((bf16_t*)out)[(hb*SEQ + sidx)*HDIM + (hc & 63)] = (bf16_t)(v * 0.125f);
                    else if (mat == 1)
                        ((bf16_t*)out_k)[(hb*SEQ + sidx)*HDIM + (hc & 63)] = (bf16_t)v;
                    else
                        ((bf16_t*)out_v)[(hb*HDIM + (hc & 63))*SEQ + sidx] = (bf16_t)v;
                }
            }
        }
    }
}

// ---------------- flash attention: swapped-QK, defer-max, cross-tile pipeline ----------------
// 1D grid 1024. XCD decode: each XCD owns 8 bh entirely -> K/V (4MB) is L2-resident.
// Per block: 4 independent waves, 32 q-rows each. Loop is software-pipelined:
//   QK(t+1) | lgkm-wait | kload(t+2) | PV(t) | vload(t+1) | SM(t+1) | Pwrite(t+1)
// so the P-write drain + P ds_reads hide under QK's MFMA cluster, and global-load
// latency hides under a full iteration of compute.
__device__ __forceinline__ void kload(bf16x8 (&dst)[4][2], const bf16_t* kb0,
                                      int ktt, int c16, int g) {
    const bf16_t* kbase = kb0 + (size_t)ktt*64*HDIM;
#pragma unroll
    for (int jk = 0; jk < 4; ++jk)
#pragma unroll
        for (int ks = 0; ks < 2; ++ks)
            dst[jk][ks] = *(const bf16x8*)(kbase + (size_t)(16*jk + c16)*HDIM + ks*32 + 8*g);
}

__device__ __forceinline__ void vload(bf16x8 (&vr)[4][2], const bf16_t* vt0,
                                      int ktt, int c16, int g) {
#pragma unroll
    for (int nf = 0; nf < 4; ++nf)
#pragma unroll
        for (int ks = 0; ks < 2; ++ks)
            vr[nf][ks] = *(const bf16x8*)(vt0 + (size_t)(16*nf + c16)*SEQ + ktt*64 + ks*32 + 8*g);
}

__device__ __forceinline__ void qk_step(f32x4 (&s)[2][4], const bf16x8 (&kr)[4][2],
                                        const bf16x8 (&aq)[2][2]) {
    const f32x4 z = {0.f, 0.f, 0.f, 0.f};
    __builtin_amdgcn_s_setprio(1);
#pragma unroll
    for (int qf = 0; qf < 2; ++qf)
#pragma unroll
        for (int jk = 0; jk < 4; ++jk) {
            s[qf][jk] = __builtin_amdgcn_mfma_f32_16x16x32_bf16(kr[jk][0], aq[qf][0], z, 0, 0, 0);
            s[qf][jk] = __builtin_amdgcn_mfma_f32_16x16x32_bf16(kr[jk][1], aq[qf][1], s[qf][jk], 0, 0, 0);
        }
    __builtin_amdgcn_s_setprio(0);
}

__device__ __forceinline__ void sm_step(f32x4 (&s)[2][4], f32x4 (&acc)[2][4],
                                        float (&m)[2], float (&ls)[2], int g) {
#pragma unroll
    for (int qf = 0; qf < 2; ++qf) {
        float a0 = fmaxf(fmaxf(s[qf][0][0], s[qf][0][1]), fmaxf(s[qf][0][2], s[qf][0][3]));
        float a1 = fmaxf(fmaxf(s[qf][1][0], s[qf][1][1]), fmaxf(s[qf][1][2], s[qf][1][3]));
        float a2 = fmaxf(fmaxf(s[qf][2][0], s[qf][2][1]), fmaxf(s[qf][2][2], s[qf][2][3]));
        float a3 = fmaxf(fmaxf(s[qf][3][0], s[qf][3][1]), fmaxf(s[qf][3][2], s[qf][3][3]));
        float pm = fmaxf(fmaxf(a0, a1), fmaxf(a2, a3));
        pm = fmaxf(pm, __shfl_xor(pm, 16, 64));
        pm = fmaxf(pm, __shfl_xor(pm, 32, 64));
        if (__any(pm > m[qf] + 8.0f)) {          // defer-max: rare after tile 0
            float mn   = fmaxf(m[qf], pm);
            float corr = __expf(m[qf] - mn);
            ls[qf] *= corr;
            m[qf]   = mn;
            float c0 = __shfl(corr, 4*g + 0, 64);
            float c1 = __shfl(corr, 4*g + 1, 64);
            float c2 = __shfl(corr, 4*g + 2, 64);
            float c3 = __shfl(corr, 4*g + 3, 64);
#pragma unroll
            for (int nf = 0; nf < 4; ++nf) {
                acc[qf][nf][0] *= c0; acc[qf][nf][1] *= c1;
                acc[qf][nf][2] *= c2; acc[qf][nf][3] *= c3;
            }
        }
        float rsum = 0.f;
#pragma unroll
        for (int jk = 0; jk < 4; ++jk)
#pragma unroll
            for (int i = 0; i < 4; ++i) {
                s[qf][jk][i] = __expf(s[qf][jk][i] - m[qf]);
                rsum += s[qf][jk][i];
            }
        rsum += __shfl_xor(rsum, 16, 64);
        rsum += __shfl_xor(rsum, 32, 64);
        ls[qf] += rsum;
    }
}

__device__ __forceinline__ void pwrite_step(const f32x4 (&s)[2][4], char* buf, int c16, int g) {
#pragma unroll
    for (int qf = 0; qf < 2; ++qf)
#pragma unroll
        for (int jk = 0; jk < 4; ++jk) {
            bf16x4 pk;
            pk[0]=(bf16_t)s[qf][jk][0]; pk[1]=(bf16_t)s[qf][jk][1];
            pk[2]=(bf16_t)s[qf][jk][2]; pk[3]=(bf16_t)s[qf][jk][3];
            *(bf16x4*)(buf + (qf*16 + c16)*128 + ((32*jk + 8*g) ^ ((c16 & 7) << 4))) = pk;
        }
}

__device__ __forceinline__ void pv_step(f32x4 (&acc)[2][4], const bf16x8 (&vr)[4][2],
                                        const char* buf, int c16, int g) {
    __builtin_amdgcn_s_setprio(1);
#pragma unroll
    for (int qf = 0; qf < 2; ++qf)
#pragma unroll
        for (int ks = 0; ks < 2; ++ks) {
            bf16x8 pa = *(const bf16x8*)(buf + (qf*16 + c16)*128 + ((ks*64 + 16*g) ^ ((c16 & 7) << 4)));
#pragma unroll
            for (int nf = 0; nf < 4; ++nf)
                acc[qf][nf] = __builtin_amdgcn_mfma_f32_16x16x32_bf16(pa, vr[nf][ks], acc[qf][nf], 0, 0, 0);
        }
    __builtin_amdgcn_s_setprio(0);
}

__global__ __launch_bounds__(256, 2) void attn_k(
    const bf16_t* __restrict__ qb, const bf16_t* __restrict__ kb,
    const bf16_t* __restrict__ vt, bf16_t* __restrict__ ctx)
{
    // XCD decode: xcd = id&7 (dispatch round-robin), 8 bh per XCD
    const int id  = blockIdx.x;
    const int idx = id >> 3;
    const int bh  = (id & 7) + 8 * (idx & 7);
    const int qt  = idx >> 3;
    const int w   = threadIdx.x >> 6;
    const int l   = threadIdx.x & 63;
    const int c16 = l & 15, g = l >> 4;
    const int q0  = qt*128 + w*32;

    __shared__ char Ps[4*8192];
    char* myP = &Ps[w*8192];

    bf16x8 aq[2][2];
#pragma unroll
    for (int qf = 0; qf < 2; ++qf) {
        const bf16_t* qrow = qb + ((size_t)bh*SEQ + q0 + qf*16 + c16)*HDIM;
        aq[qf][0] = *(const bf16x8*)(qrow + 8*g);
        aq[qf][1] = *(const bf16x8*)(qrow + 32 + 8*g);
    }

    const bf16_t* kb0 = kb + (size_t)bh*SEQ*HDIM;
    const bf16_t* vt0 = vt + (size_t)bh*HDIM*SEQ;

    f32x4 acc[2][4] = {};
    float m[2]  = {-1e30f, -1e30f};
    float ls[2] = {0.f, 0.f};

    bf16x8 kr[2][4][2], vr[4][2];
    f32x4 s[2][4];

    // prologue: tile 0
    kload(kr[0], kb0, 0, c16, g);
    vload(vr, vt0, 0, c16, g);
    kload(kr[1], kb0, 1, c16, g);
    qk_step(s, kr[0], aq);
    sm_step(s, acc, m, ls, g);
    pwrite_step(s, myP, c16, g);

    const int NT = SEQ/64;   // 32
    for (int t = 0; t < NT - 1; ++t) {
        qk_step(s, kr[(t+1)&1], aq);                         // scores for tile t+1 (MFMA only)
        asm volatile("s_waitcnt lgkmcnt(0)" ::: "memory");   // P(t) writes visible
        __builtin_amdgcn_sched_barrier(0);
        if (t + 2 < NT) kload(kr[t&1], kb0, t+2, c16, g);    // issue K(t+2) into freed buffer
        pv_step(acc, vr, myP + (t&1)*4096, c16, g);          // PV(t)
        vload(vr, vt0, t+1, c16, g);                          // issue V(t+1) (WAR after PV reads)
        __builtin_amdgcn_sched_barrier(0);                   // keep loads issued here
        sm_step(s, acc, m, ls, g);                            // softmax tile t+1
        pwrite_step(s, myP + ((t+1)&1)*4096, c16, g);        // P(t+1)
    }
    asm volatile("s_waitcnt lgkmcnt(0)" ::: "memory");
    __builtin_amdgcn_sched_barrier(0);
    pv_step(acc, vr, myP + ((NT-1)&1)*4096, c16, g);

    const int b = bh >> 4, h = bh & 15;
#pragma unroll
    for (int qf = 0; qf < 2; ++qf) {
        float i0 = 1.0f / __shfl(ls[qf], 4*g + 0, 64);
        float i1 = 1.0f / __shfl(ls[qf], 4*g + 1, 64);
        float i2 = 1.0f / __shfl(ls[qf], 4*g + 2, 64);
        float i3 = 1.0f / __shfl(ls[qf], 4*g + 3, 64);
#pragma unroll
        for (int nf = 0; nf < 4; ++nf) {
            long col = (size_t)h*HDIM + nf*16 + c16;
            long rb  = (size_t)b*SEQ + q0 + qf*16 + 4*g;
            ctx[(rb + 0)*DMODEL + col] = (bf16_t)(acc[qf][nf][0] * i0);
            ctx[(rb + 1)*DMODEL + col] = (bf16_t)(acc[qf][nf][1] * i1);
            ctx[(rb + 2)*DMODEL + col] = (bf16_t)(acc[qf][nf][2] * i2);
            ctx[(rb + 3)*DMODEL + col] = (bf16_t)(acc[qf][nf][3] * i3);
        }
    }
}

// ---------------- layer norm: one block per row of 1024 ----------------
__global__ __launch_bounds__(256) void ln_k(
    const float* __restrict__ a, const float* __restrict__ b,
    const float* __restrict__ g, const float* __restrict__ be,
    float* __restrict__ of, bf16_t* __restrict__ ob)
{
    const long row = blockIdx.x;
    const int tid = threadIdx.x;
    float4 v = ((const float4*)(a + row*DMODEL))[tid];
    if (b) {
        float4 u = ((const float4*)(b + row*DMODEL))[tid];
        v.x += u.x; v.y += u.y; v.z += u.z; v.w += u.w;
    }
    float s = v.x + v.y + v.z + v.w;
    float q = v.x*v.x + v.y*v.y + v.z*v.z + v.w*v.w;
#pragma unroll
    for (int msk = 1; msk < 64; msk <<= 1) {
        s += __shfl_xor(s, msk, 64);
        q += __shfl_xor(q, msk, 64);
    }
    __shared__ float sb[4], qb2[4];
    int w = tid >> 6, lid = tid & 63;
    if (lid == 0) { sb[w] = s; qb2[w] = q; }
    __syncthreads();
    s = sb[0] + sb[1] + sb[2] + sb[3];
    q = qb2[0] + qb2[1] + qb2[2] + qb2[3];
    float mean = s * (1.f/1024.f);
    float var  = q * (1.f/1024.f) - mean*mean;
    float rs   = rsqrtf(var + 1e-5f);
    float4 gv = ((const float4*)g)[tid];
    float4 bv = ((const float4*)be)[tid];
    float o0 = (v.x-mean)*rs*gv.x + bv.x;
    float o1 = (v.y-mean)*rs*gv.y + bv.y;
    float o2 = (v.z-mean)*rs*gv.z + bv.z;
    float o3 = (v.w-mean)*rs*gv.w + bv.w;
    if (ob) {
        bf16x4 o; o[0]=(bf16_t)o0; o[1]=(bf16_t)o1; o[2]=(bf16_t)o2; o[3]=(bf16_t)o3;
        *(bf16x4*)(ob + row*DMODEL + tid*4) = o;
    } else {
        float4 o = make_float4(o0, o1, o2, o3);
        ((float4*)(of + row*DMODEL))[tid] = o;
    }
}

// ---------------- host ----------------
extern "C" void kernel_launch(void* const* d_in, const int* in_sizes, int n_in,
                              void* d_out, int out_size, void* d_ws, size_t ws_size,
                              hipStream_t stream)
{
    const float* x   = (const float*)d_in[0];
    const float* Wq  = (const float*)d_in[1];
    const float* bq  = (const float*)d_in[2];
    const float* Wk  = (const float*)d_in[3];
    const float* bk  = (const float*)d_in[4];
    const float* Wv  = (const float*)d_in[5];
    const float* bvv = (const float*)d_in[6];
    const float* Wo  = (const float*)d_in[7];
    const float* bo  = (const float*)d_in[8];
    const float* W1  = (const float*)d_in[9];
    const float* b1  = (const float*)d_in[10];
    const float* W2  = (const float*)d_in[11];
    const float* b2  = (const float*)d_in[12];
    const float* g1  = (const float*)d_in[13];
    const float* be1 = (const float*)d_in[14];
    const float* g2  = (const float*)d_in[15];
    const float* be2 = (const float*)d_in[16];

    char* ws = (char*)d_ws;
    bf16_t* xb   = (bf16_t*)(ws + XB_OFF);
    bf16_t* qbuf = (bf16_t*)(ws + Q_OFF);
    bf16_t* kbuf = (bf16_t*)(ws + K_OFF);
    bf16_t* vtb  = (bf16_t*)(ws + VT_OFF);
    bf16_t* ffn1 = (bf16_t*)(ws + FFN1_OFF);
    bf16_t* ctxb = (bf16_t*)(ws + CTX_OFF);
    float*  out1 = (float*)(ws + OUT1_OFF);
    bf16_t* ln1b = (bf16_t*)(ws + LN1_OFF);
    bf16_t* wqkv = (bf16_t*)(ws + WQKV_OFF);
    bf16_t* wob  = (bf16_t*)(ws + WO_OFF);
    bf16_t* w1b  = (bf16_t*)(ws + W1_OFF);
    bf16_t* w2b  = (bf16_t*)(ws + W2_OFF);
    float*  biasc= (float*)(ws + OUT1_OFF);   // 3072 floats, dead before Wo writes out1
    float*  dout = (float*)d_out;

    auto cast = [&](const float* s, bf16_t* d, long n) {
        int n8 = (int)(n / 8);
        cast_bf16_k<<<(n8 + 255)/256, 256, 0, stream>>>(s, d, n8);
    };
    cast(x,  xb,  (long)MTOK*DMODEL);
    cast(Wq, wqkv,                        (long)DMODEL*DMODEL);
    cast(Wk, wqkv + (long)DMODEL*DMODEL,  (long)DMODEL*DMODEL);
    cast(Wv, wqkv + 2L*DMODEL*DMODEL,     (long)DMODEL*DMODEL);
    cast(Wo, wob, (long)DMODEL*DMODEL);
    cast(W1, w1b, (long)DFF*DMODEL);
    cast(W2, w2b, (long)DMODEL*DFF);
    concat_bias_k<<<12, 256, 0, stream>>>(bq, bk, bvv, biasc);

    dim3 blk(256);
    // fused QKV projection (Q scaled 1/8 in epilogue)
    gemm_bt<5><<<dim3(3*DMODEL/128, MTOK/128), blk, 0, stream>>>(
        xb, wqkv, biasc, qbuf, kbuf, vtb, nullptr, MTOK, 3*DMODEL, DMODEL, 1.f);
    // attention (1D grid, XCD-decoded)
    attn_k<<<dim3((SEQ/128) * 4*NHEAD), blk, 0, stream>>>(qbuf, kbuf, vtb, ctxb);
    // Wo projection -> out1 (fp32)
    gemm_bt<2><<<dim3(DMODEL/128, MTOK/128), blk, 0, stream>>>(
        ctxb, wob, bo, out1, nullptr, nullptr, nullptr, MTOK, DMODEL, DMODEL, 1.f);
    // LN1: ln1 = LN(x + out1) -> bf16
    ln_k<<<MTOK, blk, 0, stream>>>(x, out1, g1, be1, nullptr, ln1b);
    // FFN1: relu(ln1 @ W1^T + b1) -> bf16
    gemm_bt<3><<<dim3(DFF/128, MTOK/128), blk, 0, stream>>>(
        ln1b, w1b, b1, ffn1, nullptr, nullptr, nullptr, MTOK, DFF, DMODEL, 1.f);
    // FFN2: s2 = out1 + (ffn1 @ W2^T + b2) -> fp32, in place over out1
    gemm_bt<4><<<dim3(DMODEL/128, MTOK/128), blk, 0, stream>>>(
        ffn1, w2b, b2, out1, nullptr, nullptr, out1, MTOK, DMODEL, DFF, 1.f);
    // LN2 -> d_out (fp32)
    ln_k<<<MTOK, blk, 0, stream>>>(out1, nullptr, g2, be2, dout, nullptr);
}

// Round 6
// 589.355 us; speedup vs baseline: 1.2933x; 1.2933x over previous
//
#include <hip/hip_runtime.h>

typedef __bf16 bf16_t;
typedef __bf16 bf16x8 __attribute__((ext_vector_type(8)));
typedef __bf16 bf16x4 __attribute__((ext_vector_type(4)));
typedef float  f32x4  __attribute__((ext_vector_type(4)));

#define SEQ   2048
#define DMODEL 1024
#define DFF   4096
#define NHEAD 16
#define HDIM  64
#define MTOK  8192   // 4 * 2048

// ---------------- workspace layout (bytes) ----------------
#define MB (size_t)(1024*1024)
static const size_t XB_OFF   = 0;          // bf16 [8192][1024]  (aliased by FFN1 later)
static const size_t Q_OFF    = 16*MB;      // bf16 [B,H,S,64]
static const size_t K_OFF    = 32*MB;      // bf16 [B,H,S,64]
static const size_t VT_OFF   = 48*MB;      // bf16 [B,H,64,S]
static const size_t FFN1_OFF = 0;          // bf16 [8192][4096] aliases XB..VT (all dead then)
static const size_t CTX_OFF  = 64*MB;      // bf16 [8192][1024]
static const size_t OUT1_OFF = 80*MB;      // f32  [8192][1024]; bias-concat scratch earlier
static const size_t LN1_OFF  = 112*MB;     // bf16 [8192][1024]
static const size_t WQKV_OFF = 128*MB;     // bf16 [3072][1024] (Q,K,V rows concat)
static const size_t WO_OFF   = 134*MB;
static const size_t W1_OFF   = 136*MB;     // bf16 [4096][1024]
static const size_t W2_OFF   = 144*MB;     // bf16 [1024][4096]  (ends at 152MB)

// ---------------- helpers ----------------
__device__ inline void gload16(const void* g, void* l) {
    __builtin_amdgcn_global_load_lds((__attribute__((address_space(1))) void*)g,
                                     (__attribute__((address_space(3))) void*)l, 16, 0, 0);
}

__global__ __launch_bounds__(256) void cast_bf16_k(const float* __restrict__ s,
                                                   bf16_t* __restrict__ d, int n8) {
    int i = blockIdx.x * 256 + threadIdx.x;
    if (i >= n8) return;
    float4 v0 = ((const float4*)s)[2*i];
    float4 v1 = ((const float4*)s)[2*i+1];
    bf16x8 o;
    o[0]=(bf16_t)v0.x; o[1]=(bf16_t)v0.y; o[2]=(bf16_t)v0.z; o[3]=(bf16_t)v0.w;
    o[4]=(bf16_t)v1.x; o[5]=(bf16_t)v1.y; o[6]=(bf16_t)v1.z; o[7]=(bf16_t)v1.w;
    *(bf16x8*)(d + (size_t)i*8) = o;
}

__global__ __launch_bounds__(256) void concat_bias_k(const float* __restrict__ a,
                                                     const float* __restrict__ b,
                                                     const float* __restrict__ c,
                                                     float* __restrict__ o) {
    int i = blockIdx.x * 256 + threadIdx.x;   // grid 12*256 = 3072
    o[i] = (i < 1024) ? a[i] : ((i < 2048) ? b[i - 1024] : c[i - 2048]);
}

// ---------------- GEMM: C = (A(MxK) * B(NxK)^T + bias) * scale ----------------
// EPI 2: fp32 + bias -> out (out1)
// EPI 3: relu -> bf16 (ffn1)
// EPI 4: fp32 + bias + aux[r,c] -> out (s2 = out1+out2, may alias aux)
// EPI 5: fused QKV (N=3072, bias concat'd): mat0 -> Q scatter *0.125, mat1 -> K scatter,
//        mat2 -> V^T scatter. out=Q, out_k=K, out_v=V^T.
template<int EPI>
__global__ __launch_bounds__(256, 2) void gemm_bt(
    const bf16_t* __restrict__ A, const bf16_t* __restrict__ Bm,
    const float* __restrict__ bias, void* __restrict__ out,
    void* __restrict__ out_k, void* __restrict__ out_v,
    const float* __restrict__ aux, int M, int N, int K, float scale)
{
    __shared__ bf16_t As[128*64];
    __shared__ bf16_t Bs[128*64];
    const int tid = threadIdx.x;
    const int l   = tid & 63;
    const int wid = tid >> 6;
    const int wm  = wid >> 1, wn = wid & 1;
    const int c16 = l & 15,   g  = l >> 4;
    // XCD-aware bijective swizzle (all grids have nwg % 8 == 0)
    int lin = blockIdx.y * gridDim.x + blockIdx.x;
    int nwg = gridDim.x * gridDim.y;
    int swz = (lin & 7) * (nwg >> 3) + (lin >> 3);
    const long brow = (long)(swz / gridDim.x) * 128;
    const long bcol = (long)(swz % gridDim.x) * 128;

    f32x4 acc[4][4] = {};

    const int nkt = K >> 6;
    for (int kt = 0; kt < nkt; ++kt) {
        __syncthreads();   // protect LDS while other waves may still be reading
        const bf16_t* Ag = A  + brow * K + kt*64;
        const bf16_t* Bg = Bm + bcol * K + kt*64;
#pragma unroll
        for (int c = 0; c < 4; ++c) {
            int e   = (c*256 + tid) * 8;     // flat bf16 element in 128x64 tile
            int row = e >> 6;
            int col = e & 63;
            gload16(Ag + (long)row*K + col, &As[e]);
            gload16(Bg + (long)row*K + col, &Bs[e]);
        }
        __syncthreads();   // drains vmcnt(0): LDS tiles ready
#pragma unroll
        for (int kk = 0; kk < 2; ++kk) {
            bf16x8 af[4], bfr[4];
#pragma unroll
            for (int mi = 0; mi < 4; ++mi)
                af[mi] = *(const bf16x8*)&As[(wm*64 + mi*16 + c16)*64 + kk*32 + 8*g];
#pragma unroll
            for (int ni = 0; ni < 4; ++ni)
                bfr[ni] = *(const bf16x8*)&Bs[(wn*64 + ni*16 + c16)*64 + kk*32 + 8*g];
#pragma unroll
            for (int mi = 0; mi < 4; ++mi)
#pragma unroll
                for (int ni = 0; ni < 4; ++ni)
                    acc[mi][ni] = __builtin_amdgcn_mfma_f32_16x16x32_bf16(
                        af[mi], bfr[ni], acc[mi][ni], 0, 0, 0);
        }
    }

    // epilogue: lane l, reg i -> row = ...+ g*4 + i, col = ...+ c16
#pragma unroll
    for (int ni = 0; ni < 4; ++ni) {
        const long c = bcol + wn*64 + ni*16 + c16;
        const float bv = bias[c];
#pragma unroll
        for (int mi = 0; mi < 4; ++mi) {
#pragma unroll
            for (int i = 0; i < 4; ++i) {
                const long r = brow + wm*64 + mi*16 + g*4 + i;
                float v = (acc[mi][ni][i] + bv) * scale;
                if constexpr (EPI == 2) {
                    ((float*)out)[r*N + c] = v;
                } else if constexpr (EPI == 3) {
                    ((bf16_t*)out)[r*N + c] = (bf16_t)fmaxf(v, 0.f);
                } else if constexpr (EPI == 4) {
                    ((float*)out)[r*N + c] = v + aux[r*N + c];
                } else if constexpr (EPI == 5) {
                    const int mat = (int)(c >> 10);
                    const int hc  = (int)(c & 1023);
                    const long bb = r >> 11, sidx = r & (SEQ-1);
                    const long hb = bb*NHEAD + (hc >> 6);
                    if (mat == 0)
                        ((bf16_t*)out)[(hb*SEQ + sidx)*HDIM + (hc & 63)] = (bf16_t)(v * 0.125f);
                    else if (mat == 1)
                        ((bf16_t*)out_k)[(hb*SEQ + sidx)*HDIM + (hc & 63)] = (bf16_t)v;
                    else
                        ((bf16_t*)out_v)[(hb*HDIM + (hc & 63))*SEQ + sidx] = (bf16_t)v;
                }
            }
        }
    }
}

// ---------------- flash attention: swapped-QK, defer-max, static register pipeline ----------------
// 1D grid 1024. XCD decode: each XCD owns 8 bh entirely -> K/V (4MB) fits one XCD's L2.
// 4 independent waves/block, 32 q-rows each. Loop unrolled x2 with STATICALLY-NAMED
// buffers kA/kB/vA/vB (rule #20: no runtime-indexed register arrays). Per stage:
//   QK(t+1) | lgkm-wait | issue K(t+2),V(t+1) | PV(t) | SM(t+1) | Pwrite(t+1)
__device__ __forceinline__ void kload(bf16x8 (&dst)[4][2], const bf16_t* kb0,
                                      int ktt, int c16, int g) {
    const bf16_t* kbase = kb0 + (size_t)ktt*64*HDIM;
#pragma unroll
    for (int jk = 0; jk < 4; ++jk)
#pragma unroll
        for (int ks = 0; ks < 2; ++ks)
            dst[jk][ks] = *(const bf16x8*)(kbase + (size_t)(16*jk + c16)*HDIM + ks*32 + 8*g);
}

__device__ __forceinline__ void vload(bf16x8 (&vr)[4][2], const bf16_t* vt0,
                                      int ktt, int c16, int g) {
#pragma unroll
    for (int nf = 0; nf < 4; ++nf)
#pragma unroll
        for (int ks = 0; ks < 2; ++ks)
            vr[nf][ks] = *(const bf16x8*)(vt0 + (size_t)(16*nf + c16)*SEQ + ktt*64 + ks*32 + 8*g);
}

__device__ __forceinline__ void qk_step(f32x4 (&s)[2][4], const bf16x8 (&kr)[4][2],
                                        const bf16x8 (&aq)[2][2]) {
    const f32x4 z = {0.f, 0.f, 0.f, 0.f};
    __builtin_amdgcn_s_setprio(1);
#pragma unroll
    for (int qf = 0; qf < 2; ++qf)
#pragma unroll
        for (int jk = 0; jk < 4; ++jk) {
            s[qf][jk] = __builtin_amdgcn_mfma_f32_16x16x32_bf16(kr[jk][0], aq[qf][0], z, 0, 0, 0);
            s[qf][jk] = __builtin_amdgcn_mfma_f32_16x16x32_bf16(kr[jk][1], aq[qf][1], s[qf][jk], 0, 0, 0);
        }
    __builtin_amdgcn_s_setprio(0);
}

__device__ __forceinline__ void sm_step(f32x4 (&s)[2][4], f32x4 (&acc)[2][4],
                                        float (&m)[2], float (&ls)[2], int g) {
#pragma unroll
    for (int qf = 0; qf < 2; ++qf) {
        float a0 = fmaxf(fmaxf(s[qf][0][0], s[qf][0][1]), fmaxf(s[qf][0][2], s[qf][0][3]));
        float a1 = fmaxf(fmaxf(s[qf][1][0], s[qf][1][1]), fmaxf(s[qf][1][2], s[qf][1][3]));
        float a2 = fmaxf(fmaxf(s[qf][2][0], s[qf][2][1]), fmaxf(s[qf][2][2], s[qf][2][3]));
        float a3 = fmaxf(fmaxf(s[qf][3][0], s[qf][3][1]), fmaxf(s[qf][3][2], s[qf][3][3]));
        float pm = fmaxf(fmaxf(a0, a1), fmaxf(a2, a3));
        pm = fmaxf(pm, __shfl_xor(pm, 16, 64));
        pm = fmaxf(pm, __shfl_xor(pm, 32, 64));
        if (__any(pm > m[qf] + 8.0f)) {          // defer-max: rare after tile 0
            float mn   = fmaxf(m[qf], pm);
            float corr = __expf(m[qf] - mn);
            ls[qf] *= corr;
            m[qf]   = mn;
            float c0 = __shfl(corr, 4*g + 0, 64);
            float c1 = __shfl(corr, 4*g + 1, 64);
            float c2 = __shfl(corr, 4*g + 2, 64);
            float c3 = __shfl(corr, 4*g + 3, 64);
#pragma unroll
            for (int nf = 0; nf < 4; ++nf) {
                acc[qf][nf][0] *= c0; acc[qf][nf][1] *= c1;
                acc[qf][nf][2] *= c2; acc[qf][nf][3] *= c3;
            }
        }
        float rsum = 0.f;
#pragma unroll
        for (int jk = 0; jk < 4; ++jk)
#pragma unroll
            for (int i = 0; i < 4; ++i) {
                s[qf][jk][i] = __expf(s[qf][jk][i] - m[qf]);
                rsum += s[qf][jk][i];
            }
        rsum += __shfl_xor(rsum, 16, 64);
        rsum += __shfl_xor(rsum, 32, 64);
        ls[qf] += rsum;
    }
}

__device__ __forceinline__ void pwrite_step(const f32x4 (&s)[2][4], char* buf, int c16, int g) {
#pragma unroll
    for (int qf = 0; qf < 2; ++qf)
#pragma unroll
        for (int jk = 0; jk < 4; ++jk) {
            bf16x4 pk;
            pk[0]=(bf16_t)s[qf][jk][0]; pk[1]=(bf16_t)s[qf][jk][1];
            pk[2]=(bf16_t)s[qf][jk][2]; pk[3]=(bf16_t)s[qf][jk][3];
            *(bf16x4*)(buf + (qf*16 + c16)*128 + ((32*jk + 8*g) ^ ((c16 & 7) << 4))) = pk;
        }
}

__device__ __forceinline__ void pv_step(f32x4 (&acc)[2][4], const bf16x8 (&vr)[4][2],
                                        const char* buf, int c16, int g) {
    __builtin_amdgcn_s_setprio(1);
#pragma unroll
    for (int qf = 0; qf < 2; ++qf)
#pragma unroll
        for (int ks = 0; ks < 2; ++ks) {
            bf16x8 pa = *(const bf16x8*)(buf + (qf*16 + c16)*128 + ((ks*64 + 16*g) ^ ((c16 & 7) << 4)));
#pragma unroll
            for (int nf = 0; nf < 4; ++nf)
                acc[qf][nf] = __builtin_amdgcn_mfma_f32_16x16x32_bf16(pa, vr[nf][ks], acc[qf][nf], 0, 0, 0);
        }
    __builtin_amdgcn_s_setprio(0);
}

__global__ __launch_bounds__(256, 2) void attn_k(
    const bf16_t* __restrict__ qb, const bf16_t* __restrict__ kb,
    const bf16_t* __restrict__ vt, bf16_t* __restrict__ ctx)
{
    // XCD decode: xcd = id&7 (dispatch round-robin), 8 bh per XCD
    const int id  = blockIdx.x;
    const int idx = id >> 3;
    const int bh  = (id & 7) + 8 * (idx & 7);
    const int qt  = idx >> 3;
    const int w   = threadIdx.x >> 6;
    const int l   = threadIdx.x & 63;
    const int c16 = l & 15, g = l >> 4;
    const int q0  = qt*128 + w*32;

    __shared__ char Ps[4*8192];
    char* myP = &Ps[w*8192];

    bf16x8 aq[2][2];
#pragma unroll
    for (int qf = 0; qf < 2; ++qf) {
        const bf16_t* qrow = qb + ((size_t)bh*SEQ + q0 + qf*16 + c16)*HDIM;
        aq[qf][0] = *(const bf16x8*)(qrow + 8*g);
        aq[qf][1] = *(const bf16x8*)(qrow + 32 + 8*g);
    }

    const bf16_t* kb0 = kb + (size_t)bh*SEQ*HDIM;
    const bf16_t* vt0 = vt + (size_t)bh*HDIM*SEQ;

    f32x4 acc[2][4] = {};
    float m[2]  = {-1e30f, -1e30f};
    float ls[2] = {0.f, 0.f};

    bf16x8 kA[4][2], kB[4][2], vA[4][2], vB[4][2];
    f32x4 s[2][4];

    // prologue: tile 0 scores
    kload(kA, kb0, 0, c16, g);
    vload(vA, vt0, 0, c16, g);
    kload(kB, kb0, 1, c16, g);
    qk_step(s, kA, aq);
    sm_step(s, acc, m, ls, g);
    pwrite_step(s, myP, c16, g);                         // P(0) -> buf0

    const int NT = SEQ/64;   // 32
    for (int t = 0; t < NT - 2; t += 2) {
        // ---- stage A: PV(t) from buf0/vA; prepare tile t+1 ----
        qk_step(s, kB, aq);                              // QK(t+1)
        asm volatile("s_waitcnt lgkmcnt(0)" ::: "memory");  // P(t) writes visible
        __builtin_amdgcn_sched_barrier(0);
        kload(kA, kb0, t + 2, c16, g);                   // issue K(t+2) (kA free: K(t) consumed)
        vload(vB, vt0, t + 1, c16, g);                   // issue V(t+1)
        __builtin_amdgcn_sched_barrier(0);               // pin load-issue point
        pv_step(acc, vA, myP, c16, g);                   // PV(t) from buf0
        sm_step(s, acc, m, ls, g);                       // softmax tile t+1
        pwrite_step(s, myP + 4096, c16, g);              // P(t+1) -> buf1
        // ---- stage B: PV(t+1) from buf1/vB; prepare tile t+2 ----
        qk_step(s, kA, aq);                              // QK(t+2)
        asm volatile("s_waitcnt lgkmcnt(0)" ::: "memory");
        __builtin_amdgcn_sched_barrier(0);
        kload(kB, kb0, t + 3, c16, g);                   // issue K(t+3)
        vload(vA, vt0, t + 2, c16, g);                   // issue V(t+2)
        __builtin_amdgcn_sched_barrier(0);
        pv_step(acc, vB, myP + 4096, c16, g);            // PV(t+1) from buf1
        sm_step(s, acc, m, ls, g);                       // softmax tile t+2
        pwrite_step(s, myP, c16, g);                     // P(t+2) -> buf0
    }
    // epilogue: tiles NT-2 (P in buf0, V in vA) and NT-1 (K in kB)
    qk_step(s, kB, aq);                                  // QK(NT-1)
    asm volatile("s_waitcnt lgkmcnt(0)" ::: "memory");
    __builtin_amdgcn_sched_barrier(0);
    vload(vB, vt0, NT - 1, c16, g);
    __builtin_amdgcn_sched_barrier(0);
    pv_step(acc, vA, myP, c16, g);                       // PV(NT-2)
    sm_step(s, acc, m, ls, g);
    pwrite_step(s, myP + 4096, c16, g);                  // P(NT-1) -> buf1
    asm volatile("s_waitcnt lgkmcnt(0)" ::: "memory");
    __builtin_amdgcn_sched_barrier(0);
    pv_step(acc, vB, myP + 4096, c16, g);                // PV(NT-1)

    const int b = bh >> 4, h = bh & 15;
#pragma unroll
    for (int qf = 0; qf < 2; ++qf) {
        float i0 = 1.0f / __shfl(ls[qf], 4*g + 0, 64);
        float i1 = 1.0f / __shfl(ls[qf], 4*g + 1, 64);
        float i2 = 1.0f / __shfl(ls[qf], 4*g + 2, 64);
        float i3 = 1.0f / __shfl(ls[qf], 4*g + 3, 64);
#pragma unroll
        for (int nf = 0; nf < 4; ++nf) {
            long col = (size_t)h*HDIM + nf*16 + c16;
            long rb  = (size_t)b*SEQ + q0 + qf*16 + 4*g;
            ctx[(rb + 0)*DMODEL + col] = (bf16_t)(acc[qf][nf][0] * i0);
            ctx[(rb + 1)*DMODEL + col] = (bf16_t)(acc[qf][nf][1] * i1);
            ctx[(rb + 2)*DMODEL + col] = (bf16_t)(acc[qf][nf][2] * i2);
            ctx[(rb + 3)*DMODEL + col] = (bf16_t)(acc[qf][nf][3] * i3);
        }
    }
}

// ---------------- layer norm: one block per row of 1024 ----------------
__global__ __launch_bounds__(256) void ln_k(
    const float* __restrict__ a, const float* __restrict__ b,
    const float* __restrict__ g, const float* __restrict__ be,
    float* __restrict__ of, bf16_t* __restrict__ ob)
{
    const long row = blockIdx.x;
    const int tid = threadIdx.x;
    float4 v = ((const float4*)(a + row*DMODEL))[tid];
    if (b) {
        float4 u = ((const float4*)(b + row*DMODEL))[tid];
        v.x += u.x; v.y += u.y; v.z += u.z; v.w += u.w;
    }
    float s = v.x + v.y + v.z + v.w;
    float q = v.x*v.x + v.y*v.y + v.z*v.z + v.w*v.w;
#pragma unroll
    for (int msk = 1; msk < 64; msk <<= 1) {
        s += __shfl_xor(s, msk, 64);
        q += __shfl_xor(q, msk, 64);
    }
    __shared__ float sb[4], qb2[4];
    int w = tid >> 6, lid = tid & 63;
    if (lid == 0) { sb[w] = s; qb2[w] = q; }
    __syncthreads();
    s = sb[0] + sb[1] + sb[2] + sb[3];
    q = qb2[0] + qb2[1] + qb2[2] + qb2[3];
    float mean = s * (1.f/1024.f);
    float var  = q * (1.f/1024.f) - mean*mean;
    float rs   = rsqrtf(var + 1e-5f);
    float4 gv = ((const float4*)g)[tid];
    float4 bv = ((const float4*)be)[tid];
    float o0 = (v.x-mean)*rs*gv.x + bv.x;
    float o1 = (v.y-mean)*rs*gv.y + bv.y;
    float o2 = (v.z-mean)*rs*gv.z + bv.z;
    float o3 = (v.w-mean)*rs*gv.w + bv.w;
    if (ob) {
        bf16x4 o; o[0]=(bf16_t)o0; o[1]=(bf16_t)o1; o[2]=(bf16_t)o2; o[3]=(bf16_t)o3;
        *(bf16x4*)(ob + row*DMODEL + tid*4) = o;
    } else {
        float4 o = make_float4(o0, o1, o2, o3);
        ((float4*)(of + row*DMODEL))[tid] = o;
    }
}

// ---------------- host ----------------
extern "C" void kernel_launch(void* const* d_in, const int* in_sizes, int n_in,
                              void* d_out, int out_size, void* d_ws, size_t ws_size,
                              hipStream_t stream)
{
    const float* x   = (const float*)d_in[0];
    const float* Wq  = (const float*)d_in[1];
    const float* bq  = (const float*)d_in[2];
    const float* Wk  = (const float*)d_in[3];
    const float* bk  = (const float*)d_in[4];
    const float* Wv  = (const float*)d_in[5];
    const float* bvv = (const float*)d_in[6];
    const float* Wo  = (const float*)d_in[7];
    const float* bo  = (const float*)d_in[8];
    const float* W1  = (const float*)d_in[9];
    const float* b1  = (const float*)d_in[10];
    const float* W2  = (const float*)d_in[11];
    const float* b2  = (const float*)d_in[12];
    const float* g1  = (const float*)d_in[13];
    const float* be1 = (const float*)d_in[14];
    const float* g2  = (const float*)d_in[15];
    const float* be2 = (const float*)d_in[16];

    char* ws = (char*)d_ws;
    bf16_t* xb   = (bf16_t*)(ws + XB_OFF);
    bf16_t* qbuf = (bf16_t*)(ws + Q_OFF);
    bf16_t* kbuf = (bf16_t*)(ws + K_OFF);
    bf16_t* vtb  = (bf16_t*)(ws + VT_OFF);
    bf16_t* ffn1 = (bf16_t*)(ws + FFN1_OFF);
    bf16_t* ctxb = (bf16_t*)(ws + CTX_OFF);
    float*  out1 = (float*)(ws + OUT1_OFF);
    bf16_t* ln1b = (bf16_t*)(ws + LN1_OFF);
    bf16_t* wqkv = (bf16_t*)(ws + WQKV_OFF);
    bf16_t* wob  = (bf16_t*)(ws + WO_OFF);
    bf16_t* w1b  = (bf16_t*)(ws + W1_OFF);
    bf16_t* w2b  = (bf16_t*)(ws + W2_OFF);
    float*  biasc= (float*)(ws + OUT1_OFF);   // 3072 floats, dead before Wo writes out1
    float*  dout = (float*)d_out;

    auto cast = [&](const float* s, bf16_t* d, long n) {
        int n8 = (int)(n / 8);
        cast_bf16_k<<<(n8 + 255)/256, 256, 0, stream>>>(s, d, n8);
    };
    cast(x,  xb,  (long)MTOK*DMODEL);
    cast(Wq, wqkv,                        (long)DMODEL*DMODEL);
    cast(Wk, wqkv + (long)DMODEL*DMODEL,  (long)DMODEL*DMODEL);
    cast(Wv, wqkv + 2L*DMODEL*DMODEL,     (long)DMODEL*DMODEL);
    cast(Wo, wob, (long)DMODEL*DMODEL);
    cast(W1, w1b, (long)DFF*DMODEL);
    cast(W2, w2b, (long)DMODEL*DFF);
    concat_bias_k<<<12, 256, 0, stream>>>(bq, bk, bvv, biasc);

    dim3 blk(256);
    // fused QKV projection (Q scaled 1/8 in epilogue)
    gemm_bt<5><<<dim3(3*DMODEL/128, MTOK/128), blk, 0, stream>>>(
        xb, wqkv, biasc, qbuf, kbuf, vtb, nullptr, MTOK, 3*DMODEL, DMODEL, 1.f);
    // attention (1D grid, XCD-decoded)
    attn_k<<<dim3((SEQ/128) * 4*NHEAD), blk, 0, stream>>>(qbuf, kbuf, vtb, ctxb);
    // Wo projection -> out1 (fp32)
    gemm_bt<2><<<dim3(DMODEL/128, MTOK/128), blk, 0, stream>>>(
        ctxb, wob, bo, out1, nullptr, nullptr, nullptr, MTOK, DMODEL, DMODEL, 1.f);
    // LN1: ln1 = LN(x + out1) -> bf16
    ln_k<<<MTOK, blk, 0, stream>>>(x, out1, g1, be1, nullptr, ln1b);
    // FFN1: relu(ln1 @ W1^T + b1) -> bf16
    gemm_bt<3><<<dim3(DFF/128, MTOK/128), blk, 0, stream>>>(
        ln1b, w1b, b1, ffn1, nullptr, nullptr, nullptr, MTOK, DFF, DMODEL, 1.f);
    // FFN2: s2 = out1 + (ffn1 @ W2^T + b2) -> fp32, in place over out1
    gemm_bt<4><<<dim3(DMODEL/128, MTOK/128), blk, 0, stream>>>(
        ffn1, w2b, b2, out1, nullptr, nullptr, out1, MTOK, DMODEL, DFF, 1.f);
    // LN2 -> d_out (fp32)
    ln_k<<<MTOK, blk, 0, stream>>>(out1, nullptr, g2, be2, dout, nullptr);
}